// Round 6
// baseline (374.103 us; speedup 1.0000x reference)
//
#include <hip/hip_runtime.h>

#define NN  40000
#define NE  640000
#define ND  128
#define ED  64
#define NH  8
#define DK  16

#define SCAN_NBLK 157   // ceil(40000/256)

// ---------------- fused Q/K/V projection: 16 rows/block ----------------
__global__ __launch_bounds__(256) void proj_qkv(const float* __restrict__ x,
                                                const float* __restrict__ wq,
                                                const float* __restrict__ bq,
                                                const float* __restrict__ wk,
                                                const float* __restrict__ bk,
                                                const float* __restrict__ wv,
                                                const float* __restrict__ bv,
                                                float* __restrict__ Q,
                                                float* __restrict__ K,
                                                float* __restrict__ V) {
  __shared__ float xs[ND][20];
  const int r0 = blockIdx.x * 16;
  const int tid = threadIdx.x;
  for (int i = tid; i < 16 * ND; i += 256) {
    int r = i >> 7, c = i & 127;
    xs[c][r] = x[(size_t)(r0 + r) * ND + c];
  }
  __syncthreads();

  const int o = tid & 127;
  const int half = tid >> 7;
  float aq[8], ak[8], av[8];
#pragma unroll
  for (int j = 0; j < 8; ++j) { aq[j] = 0.f; ak[j] = 0.f; av[j] = 0.f; }

#pragma unroll 4
  for (int k = 0; k < ND; ++k) {
    float4 xa = *(const float4*)&xs[k][half * 8];
    float4 xb = *(const float4*)&xs[k][half * 8 + 4];
    float wqv = wq[k * ND + o];
    float wkv = wk[k * ND + o];
    float wvv = wv[k * ND + o];
    aq[0] = fmaf(xa.x, wqv, aq[0]); aq[1] = fmaf(xa.y, wqv, aq[1]);
    aq[2] = fmaf(xa.z, wqv, aq[2]); aq[3] = fmaf(xa.w, wqv, aq[3]);
    aq[4] = fmaf(xb.x, wqv, aq[4]); aq[5] = fmaf(xb.y, wqv, aq[5]);
    aq[6] = fmaf(xb.z, wqv, aq[6]); aq[7] = fmaf(xb.w, wqv, aq[7]);
    ak[0] = fmaf(xa.x, wkv, ak[0]); ak[1] = fmaf(xa.y, wkv, ak[1]);
    ak[2] = fmaf(xa.z, wkv, ak[2]); ak[3] = fmaf(xa.w, wkv, ak[3]);
    ak[4] = fmaf(xb.x, wkv, ak[4]); ak[5] = fmaf(xb.y, wkv, ak[5]);
    ak[6] = fmaf(xb.z, wkv, ak[6]); ak[7] = fmaf(xb.w, wkv, ak[7]);
    av[0] = fmaf(xa.x, wvv, av[0]); av[1] = fmaf(xa.y, wvv, av[1]);
    av[2] = fmaf(xa.z, wvv, av[2]); av[3] = fmaf(xa.w, wvv, av[3]);
    av[4] = fmaf(xb.x, wvv, av[4]); av[5] = fmaf(xb.y, wvv, av[5]);
    av[6] = fmaf(xb.z, wvv, av[6]); av[7] = fmaf(xb.w, wvv, av[7]);
  }
  const float bqv = bq[o], bkv = bk[o], bvv = bv[o];
  const size_t base = (size_t)(r0 + half * 8) * ND + o;
#pragma unroll
  for (int j = 0; j < 8; ++j) {
    Q[base + (size_t)j * ND] = aq[j] + bqv;
    K[base + (size_t)j * ND] = ak[j] + bkv;
    V[base + (size_t)j * ND] = av[j] + bvv;
  }
}

// ---------------- out = msgn @ W + b: 16 rows/block ----------------
__global__ __launch_bounds__(256) void proj128(const float* __restrict__ x,
                                               const float* __restrict__ W,
                                               const float* __restrict__ b,
                                               float* __restrict__ y) {
  __shared__ float xs[ND][20];
  const int r0 = blockIdx.x * 16;
  const int tid = threadIdx.x;
  for (int i = tid; i < 16 * ND; i += 256) {
    int r = i >> 7, c = i & 127;
    xs[c][r] = x[(size_t)(r0 + r) * ND + c];
  }
  __syncthreads();
  const int o = tid & 127;
  const int half = tid >> 7;
  float a[8];
#pragma unroll
  for (int j = 0; j < 8; ++j) a[j] = 0.f;
#pragma unroll 8
  for (int k = 0; k < ND; ++k) {
    float4 xa = *(const float4*)&xs[k][half * 8];
    float4 xb = *(const float4*)&xs[k][half * 8 + 4];
    float w = W[k * ND + o];
    a[0] = fmaf(xa.x, w, a[0]); a[1] = fmaf(xa.y, w, a[1]);
    a[2] = fmaf(xa.z, w, a[2]); a[3] = fmaf(xa.w, w, a[3]);
    a[4] = fmaf(xb.x, w, a[4]); a[5] = fmaf(xb.y, w, a[5]);
    a[6] = fmaf(xb.z, w, a[6]); a[7] = fmaf(xb.w, w, a[7]);
  }
  const float bb = b[o];
  const size_t base = (size_t)(r0 + half * 8) * ND + o;
#pragma unroll
  for (int j = 0; j < 8; ++j) y[base + (size_t)j * ND] = a[j] + bb;
}

// ---------------- CSR build ----------------
__global__ __launch_bounds__(256) void k_hist(const int* __restrict__ ei,
                                              int* __restrict__ hist) {
  int e = blockIdx.x * 256 + threadIdx.x;
  if (e < NE) atomicAdd(&hist[ei[e]], 1);
}

__global__ __launch_bounds__(256) void k_scan1(const int* __restrict__ hist,
                                               int* __restrict__ off,
                                               int* __restrict__ bsum) {
  __shared__ int sh[256];
  const int tid = threadIdx.x;
  const int idx = blockIdx.x * 256 + tid;
  int v = (idx < NN) ? hist[idx] : 0;
  sh[tid] = v;
  __syncthreads();
#pragma unroll
  for (int d = 1; d < 256; d <<= 1) {
    int t = (tid >= d) ? sh[tid - d] : 0;
    __syncthreads();
    sh[tid] += t;
    __syncthreads();
  }
  if (idx < NN) off[idx] = sh[tid] - v;
  if (tid == 255) bsum[blockIdx.x] = sh[255];
}

__global__ __launch_bounds__(256) void k_scan2(int* __restrict__ bsum) {
  __shared__ int sh[256];
  const int tid = threadIdx.x;
  int v = (tid < SCAN_NBLK) ? bsum[tid] : 0;
  sh[tid] = v;
  __syncthreads();
#pragma unroll
  for (int d = 1; d < 256; d <<= 1) {
    int t = (tid >= d) ? sh[tid - d] : 0;
    __syncthreads();
    sh[tid] += t;
    __syncthreads();
  }
  if (tid < SCAN_NBLK) bsum[tid] = sh[tid] - v;
}

__global__ __launch_bounds__(256) void k_scan3(int* __restrict__ off,
                                               const int* __restrict__ bsum,
                                               int* __restrict__ cursor) {
  const int idx = blockIdx.x * 256 + threadIdx.x;
  if (idx < NN) {
    int o = off[idx] + bsum[blockIdx.x];
    off[idx] = o;
    cursor[idx] = o;
  }
  if (blockIdx.x == 0 && threadIdx.x == 0) off[NN] = NE;
}

__global__ __launch_bounds__(256) void k_scatter(const int* __restrict__ ei,
                                                 int* __restrict__ cursor,
                                                 int2* __restrict__ pair) {
  int e = blockIdx.x * 256 + threadIdx.x;
  if (e >= NE) return;
  int row = ei[e];
  int col = ei[NE + e];
  int pos = atomicAdd(&cursor[row], 1);
  pair[pos] = make_int2(col, e);
}

// ---------------- fused gather: software-pipelined, ping-pong LDS ----------------
// 32 lanes per node: lane l=(h<<2)|q. Chunk = 8 edges. Pipeline:
//   iter t: issue K/V(t,4-7); compute edges 0-3 (loads from iter t-1);
//           ds_write ea(t+1) (regs from t-1); load ea(t+2)->regs;
//           load cols(t+1) + issue K/V(t+1,0-3); compute edges 4-7.
// pair[] has 32-entry zeroed slack -> no clamps; invalid edges masked es=0.
#define EA_ACC(sc, cidx) do { \
  const float4* _ep = (const float4*)(ldsb + (cidx) * ED + q * 16); \
  float4 _a; \
  _a = _ep[0]; sc = fmaf(_a.x, gg[0], sc);  sc = fmaf(_a.y, gg[1], sc);  sc = fmaf(_a.z, gg[2], sc);  sc = fmaf(_a.w, gg[3], sc); \
  _a = _ep[1]; sc = fmaf(_a.x, gg[4], sc);  sc = fmaf(_a.y, gg[5], sc);  sc = fmaf(_a.z, gg[6], sc);  sc = fmaf(_a.w, gg[7], sc); \
  _a = _ep[2]; sc = fmaf(_a.x, gg[8], sc);  sc = fmaf(_a.y, gg[9], sc);  sc = fmaf(_a.z, gg[10], sc); sc = fmaf(_a.w, gg[11], sc); \
  _a = _ep[3]; sc = fmaf(_a.x, gg[12], sc); sc = fmaf(_a.y, gg[13], sc); sc = fmaf(_a.z, gg[14], sc); sc = fmaf(_a.w, gg[15], sc); \
} while (0)

#define FINISH(sc, vv, validc) do { \
  sc += __shfl_xor(sc, 1); sc += __shfl_xor(sc, 2); \
  float _es = (validc) ? __expf(fmaf(sc, 0.25f, sb)) : 0.f; \
  den += _es; \
  acc.x = fmaf(_es, (vv).x, acc.x); acc.y = fmaf(_es, (vv).y, acc.y); \
  acc.z = fmaf(_es, (vv).z, acc.z); acc.w = fmaf(_es, (vv).w, acc.w); \
} while (0)

__global__ __launch_bounds__(256) void k_gather(const float* __restrict__ Q,
                                                const float* __restrict__ K,
                                                const float* __restrict__ V,
                                                const float* __restrict__ we,
                                                const float* __restrict__ be,
                                                const float* __restrict__ ea,
                                                const int* __restrict__ off,
                                                const int2* __restrict__ pair,
                                                float* __restrict__ msgn) {
  __shared__ float eas[8][2][8 * ED];   // ping-pong: 32 KB/block
  const int g = threadIdx.x >> 5;
  const int n = blockIdx.x * 8 + g;
  const int l = threadIdx.x & 31;
  const int h = l >> 2;
  const int q = l & 3;
  const int me = l >> 2;   // staged edge (0..7)
  const int mp = l & 3;    // staged float4-part

  // ---- per-node setup: Q frag, sb, gg ----
  float qf[DK];
  {
    const float4* qp = (const float4*)(Q + (size_t)n * ND + h * DK);
#pragma unroll
    for (int i = 0; i < 4; ++i) {
      float4 v = qp[i];
      qf[4 * i + 0] = v.x; qf[4 * i + 1] = v.y;
      qf[4 * i + 2] = v.z; qf[4 * i + 3] = v.w;
    }
  }
  float sbase = 0.f;
  {
    const float4* bp = (const float4*)(be + h * DK);
#pragma unroll
    for (int i = 0; i < 4; ++i) {
      float4 b = bp[i];
      sbase = fmaf(qf[4 * i + 0], b.x, sbase);
      sbase = fmaf(qf[4 * i + 1], b.y, sbase);
      sbase = fmaf(qf[4 * i + 2], b.z, sbase);
      sbase = fmaf(qf[4 * i + 3], b.w, sbase);
    }
  }
  const float sb = sbase * 0.25f;

  float gg[16];
#pragma unroll
  for (int jj = 0; jj < 16; ++jj) {
    const float4* wp = (const float4*)(we + (size_t)(q * 16 + jj) * ND + h * DK);
    float s = 0.f;
#pragma unroll
    for (int i = 0; i < 4; ++i) {
      float4 w = wp[i];
      s = fmaf(qf[4 * i + 0], w.x, s);
      s = fmaf(qf[4 * i + 1], w.y, s);
      s = fmaf(qf[4 * i + 2], w.z, s);
      s = fmaf(qf[4 * i + 3], w.w, s);
    }
    gg[jj] = s;
  }

  float4 qv;
  qv.x = qf[q * 4 + 0]; qv.y = qf[q * 4 + 1];
  qv.z = qf[q * 4 + 2]; qv.w = qf[q * 4 + 3];

  const int j0 = off[n], j1 = off[n + 1];
  const int nch = (j1 - j0 + 7) >> 3;
  const int hq = h * DK + q * 4;

  float4 acc = make_float4(0.f, 0.f, 0.f, 0.f);
  float den = 0.f;

  // ---- pipeline prologue ----
  // ea(0) -> LDS[0]
  {
    const int eid = pair[j0 + me].y;
    const float4* s = (const float4*)(ea + (size_t)eid * ED) + mp;
    float4 a0 = s[0], a1 = s[4], a2 = s[8], a3 = s[12];
    float4* d = (float4*)&eas[g][0][me * ED] + mp;
    d[0] = a0; d[4] = a1; d[8] = a2; d[12] = a3;
  }
  // ea(1) -> regs
  float4 er0, er1, er2, er3;
  {
    const int eid = pair[j0 + 8 + me].y;
    const float4* s = (const float4*)(ea + (size_t)eid * ED) + mp;
    er0 = s[0]; er1 = s[4]; er2 = s[8]; er3 = s[12];
  }
  // cols(0) + K/V(0, edges 0-3)
  int cc0 = pair[j0 + 0].x, cc1 = pair[j0 + 1].x, cc2 = pair[j0 + 2].x, cc3 = pair[j0 + 3].x;
  int cc4 = pair[j0 + 4].x, cc5 = pair[j0 + 5].x, cc6 = pair[j0 + 6].x, cc7 = pair[j0 + 7].x;
  float4 kA0 = *(const float4*)(K + (size_t)cc0 * ND + hq);
  float4 kA1 = *(const float4*)(K + (size_t)cc1 * ND + hq);
  float4 kA2 = *(const float4*)(K + (size_t)cc2 * ND + hq);
  float4 kA3 = *(const float4*)(K + (size_t)cc3 * ND + hq);
  float4 vA0 = *(const float4*)(V + (size_t)cc0 * ND + hq);
  float4 vA1 = *(const float4*)(V + (size_t)cc1 * ND + hq);
  float4 vA2 = *(const float4*)(V + (size_t)cc2 * ND + hq);
  float4 vA3 = *(const float4*)(V + (size_t)cc3 * ND + hq);

  int cur = 0;
  for (int t = 0; t < nch; ++t) {
    const int jp = j0 + t * 8;
    const float* ldsb = &eas[g][cur][0];

    // A: issue K/V for edges 4-7 of chunk t
    float4 kB0 = *(const float4*)(K + (size_t)cc4 * ND + hq);
    float4 kB1 = *(const float4*)(K + (size_t)cc5 * ND + hq);
    float4 kB2 = *(const float4*)(K + (size_t)cc6 * ND + hq);
    float4 kB3 = *(const float4*)(K + (size_t)cc7 * ND + hq);
    float4 vB0 = *(const float4*)(V + (size_t)cc4 * ND + hq);
    float4 vB1 = *(const float4*)(V + (size_t)cc5 * ND + hq);
    float4 vB2 = *(const float4*)(V + (size_t)cc6 * ND + hq);
    float4 vB3 = *(const float4*)(V + (size_t)cc7 * ND + hq);

    // C: pair line for ea(t+2) (also prefetches cols(t+2) line)
    const int eidN = pair[jp + 16 + me].y;

    // D: compute edges 0-3 (LDS[cur] + kA/vA)
    asm volatile("s_waitcnt lgkmcnt(0)" ::: "memory");
    __builtin_amdgcn_sched_barrier(0);
    {
      float s0 = fmaf(qv.w, kA0.w, fmaf(qv.z, kA0.z, fmaf(qv.y, kA0.y, kA0.x * qv.x)));
      float s1 = fmaf(qv.w, kA1.w, fmaf(qv.z, kA1.z, fmaf(qv.y, kA1.y, kA1.x * qv.x)));
      float s2 = fmaf(qv.w, kA2.w, fmaf(qv.z, kA2.z, fmaf(qv.y, kA2.y, kA2.x * qv.x)));
      float s3 = fmaf(qv.w, kA3.w, fmaf(qv.z, kA3.z, fmaf(qv.y, kA3.y, kA3.x * qv.x)));
      EA_ACC(s0, 0); EA_ACC(s1, 1); EA_ACC(s2, 2); EA_ACC(s3, 3);
      FINISH(s0, vA0, jp + 0 < j1);
      FINISH(s1, vA1, jp + 1 < j1);
      FINISH(s2, vA2, jp + 2 < j1);
      FINISH(s3, vA3, jp + 3 < j1);
    }

    // B: ds_write ea(t+1) -> LDS[cur^1]
    {
      float4* d = (float4*)&eas[g][cur ^ 1][me * ED] + mp;
      d[0] = er0; d[4] = er1; d[8] = er2; d[12] = er3;
    }

    // E: load ea(t+2) -> regs
    {
      const float4* s = (const float4*)(ea + (size_t)eidN * ED) + mp;
      er0 = s[0]; er1 = s[4]; er2 = s[8]; er3 = s[12];
    }

    // F: cols(t+1) + issue K/V(t+1, edges 0-3)
    cc0 = pair[jp + 8].x;  cc1 = pair[jp + 9].x;  cc2 = pair[jp + 10].x; cc3 = pair[jp + 11].x;
    cc4 = pair[jp + 12].x; cc5 = pair[jp + 13].x; cc6 = pair[jp + 14].x; cc7 = pair[jp + 15].x;
    kA0 = *(const float4*)(K + (size_t)cc0 * ND + hq);
    kA1 = *(const float4*)(K + (size_t)cc1 * ND + hq);
    kA2 = *(const float4*)(K + (size_t)cc2 * ND + hq);
    kA3 = *(const float4*)(K + (size_t)cc3 * ND + hq);
    vA0 = *(const float4*)(V + (size_t)cc0 * ND + hq);
    vA1 = *(const float4*)(V + (size_t)cc1 * ND + hq);
    vA2 = *(const float4*)(V + (size_t)cc2 * ND + hq);
    vA3 = *(const float4*)(V + (size_t)cc3 * ND + hq);

    // G: compute edges 4-7 (LDS[cur] + kB/vB)
    {
      float s0 = fmaf(qv.w, kB0.w, fmaf(qv.z, kB0.z, fmaf(qv.y, kB0.y, kB0.x * qv.x)));
      float s1 = fmaf(qv.w, kB1.w, fmaf(qv.z, kB1.z, fmaf(qv.y, kB1.y, kB1.x * qv.x)));
      float s2 = fmaf(qv.w, kB2.w, fmaf(qv.z, kB2.z, fmaf(qv.y, kB2.y, kB2.x * qv.x)));
      float s3 = fmaf(qv.w, kB3.w, fmaf(qv.z, kB3.z, fmaf(qv.y, kB3.y, kB3.x * qv.x)));
      EA_ACC(s0, 4); EA_ACC(s1, 5); EA_ACC(s2, 6); EA_ACC(s3, 7);
      FINISH(s0, vB0, jp + 4 < j1);
      FINISH(s1, vB1, jp + 5 < j1);
      FINISH(s2, vB2, jp + 6 < j1);
      FINISH(s3, vB3, jp + 7 < j1);
    }

    cur ^= 1;
  }

  const float inv = 1.f / (den + 1e-8f);
  float4 o;
  o.x = acc.x * inv; o.y = acc.y * inv; o.z = acc.z * inv; o.w = acc.w * inv;
  *(float4*)(msgn + (size_t)n * ND + h * DK + q * 4) = o;
}

extern "C" void kernel_launch(void* const* d_in, const int* in_sizes, int n_in,
                              void* d_out, int out_size, void* d_ws, size_t ws_size,
                              hipStream_t stream) {
  const float* nodes = (const float*)d_in[0];
  const int*   ei    = (const int*)d_in[1];
  const float* ea    = (const float*)d_in[2];
  const float* wq    = (const float*)d_in[3];
  const float* bq    = (const float*)d_in[4];
  const float* wk    = (const float*)d_in[5];
  const float* bk    = (const float*)d_in[6];
  const float* wv    = (const float*)d_in[7];
  const float* bv    = (const float*)d_in[8];
  const float* we    = (const float*)d_in[9];
  const float* be    = (const float*)d_in[10];
  const float* wo    = (const float*)d_in[11];
  const float* bo    = (const float*)d_in[12];
  float* out = (float*)d_out;

  float* ws = (float*)d_ws;
  const size_t NND = (size_t)NN * ND;
  float* Q    = ws;
  float* K    = Q + NND;
  float* V    = K + NND;
  float* msgn = V + NND;
  int* hist   = (int*)(msgn + NND);
  int* off    = hist + NN;            // NN+1 (padded to 40004)
  int* cursor = off + 40004;
  int* bsum   = cursor + NN;
  int2* pair  = (int2*)(bsum + 256);  // NE + 32 slack int2

  hipMemsetAsync(hist, 0, NN * sizeof(int), stream);
  hipMemsetAsync(pair + NE, 0, 32 * sizeof(int2), stream);  // pipeline overrun slack

  dim3 blk(256);

  proj_qkv<<<dim3(NN / 16), blk, 0, stream>>>(nodes, wq, bq, wk, bk, wv, bv, Q, K, V);

  dim3 gE((NE + 255) / 256);
  k_hist<<<gE, blk, 0, stream>>>(ei, hist);
  k_scan1<<<dim3(SCAN_NBLK), blk, 0, stream>>>(hist, off, bsum);
  k_scan2<<<dim3(1), blk, 0, stream>>>(bsum);
  k_scan3<<<dim3(SCAN_NBLK), blk, 0, stream>>>(off, bsum, cursor);
  k_scatter<<<gE, blk, 0, stream>>>(ei, cursor, pair);

  k_gather<<<dim3(NN / 8), blk, 0, stream>>>(Q, K, V, we, be, ea, off, pair, msgn);

  proj128<<<dim3(NN / 16), blk, 0, stream>>>(msgn, wo, bo, out);
}

// Round 7
// 367.342 us; speedup vs baseline: 1.0184x; 1.0184x over previous
//
#include <hip/hip_runtime.h>

#define NN  40000
#define NE  640000
#define ND  128
#define ED  64
#define NH  8
#define DK  16

#define SCAN_NBLK 157   // ceil(40000/256)

// ---------------- fused Q/K/V projection: 16 rows/block ----------------
__global__ __launch_bounds__(256) void proj_qkv(const float* __restrict__ x,
                                                const float* __restrict__ wq,
                                                const float* __restrict__ bq,
                                                const float* __restrict__ wk,
                                                const float* __restrict__ bk,
                                                const float* __restrict__ wv,
                                                const float* __restrict__ bv,
                                                float* __restrict__ Q,
                                                float* __restrict__ K,
                                                float* __restrict__ V) {
  __shared__ float xs[ND][20];
  const int r0 = blockIdx.x * 16;
  const int tid = threadIdx.x;
  for (int i = tid; i < 16 * ND; i += 256) {
    int r = i >> 7, c = i & 127;
    xs[c][r] = x[(size_t)(r0 + r) * ND + c];
  }
  __syncthreads();

  const int o = tid & 127;
  const int half = tid >> 7;
  float aq[8], ak[8], av[8];
#pragma unroll
  for (int j = 0; j < 8; ++j) { aq[j] = 0.f; ak[j] = 0.f; av[j] = 0.f; }

#pragma unroll 4
  for (int k = 0; k < ND; ++k) {
    float4 xa = *(const float4*)&xs[k][half * 8];
    float4 xb = *(const float4*)&xs[k][half * 8 + 4];
    float wqv = wq[k * ND + o];
    float wkv = wk[k * ND + o];
    float wvv = wv[k * ND + o];
    aq[0] = fmaf(xa.x, wqv, aq[0]); aq[1] = fmaf(xa.y, wqv, aq[1]);
    aq[2] = fmaf(xa.z, wqv, aq[2]); aq[3] = fmaf(xa.w, wqv, aq[3]);
    aq[4] = fmaf(xb.x, wqv, aq[4]); aq[5] = fmaf(xb.y, wqv, aq[5]);
    aq[6] = fmaf(xb.z, wqv, aq[6]); aq[7] = fmaf(xb.w, wqv, aq[7]);
    ak[0] = fmaf(xa.x, wkv, ak[0]); ak[1] = fmaf(xa.y, wkv, ak[1]);
    ak[2] = fmaf(xa.z, wkv, ak[2]); ak[3] = fmaf(xa.w, wkv, ak[3]);
    ak[4] = fmaf(xb.x, wkv, ak[4]); ak[5] = fmaf(xb.y, wkv, ak[5]);
    ak[6] = fmaf(xb.z, wkv, ak[6]); ak[7] = fmaf(xb.w, wkv, ak[7]);
    av[0] = fmaf(xa.x, wvv, av[0]); av[1] = fmaf(xa.y, wvv, av[1]);
    av[2] = fmaf(xa.z, wvv, av[2]); av[3] = fmaf(xa.w, wvv, av[3]);
    av[4] = fmaf(xb.x, wvv, av[4]); av[5] = fmaf(xb.y, wvv, av[5]);
    av[6] = fmaf(xb.z, wvv, av[6]); av[7] = fmaf(xb.w, wvv, av[7]);
  }
  const float bqv = bq[o], bkv = bk[o], bvv = bv[o];
  const size_t base = (size_t)(r0 + half * 8) * ND + o;
#pragma unroll
  for (int j = 0; j < 8; ++j) {
    Q[base + (size_t)j * ND] = aq[j] + bqv;
    K[base + (size_t)j * ND] = ak[j] + bkv;
    V[base + (size_t)j * ND] = av[j] + bvv;
  }
}

// ---------------- out = msgn @ W + b: 16 rows/block ----------------
__global__ __launch_bounds__(256) void proj128(const float* __restrict__ x,
                                               const float* __restrict__ W,
                                               const float* __restrict__ b,
                                               float* __restrict__ y) {
  __shared__ float xs[ND][20];
  const int r0 = blockIdx.x * 16;
  const int tid = threadIdx.x;
  for (int i = tid; i < 16 * ND; i += 256) {
    int r = i >> 7, c = i & 127;
    xs[c][r] = x[(size_t)(r0 + r) * ND + c];
  }
  __syncthreads();
  const int o = tid & 127;
  const int half = tid >> 7;
  float a[8];
#pragma unroll
  for (int j = 0; j < 8; ++j) a[j] = 0.f;
#pragma unroll 8
  for (int k = 0; k < ND; ++k) {
    float4 xa = *(const float4*)&xs[k][half * 8];
    float4 xb = *(const float4*)&xs[k][half * 8 + 4];
    float w = W[k * ND + o];
    a[0] = fmaf(xa.x, w, a[0]); a[1] = fmaf(xa.y, w, a[1]);
    a[2] = fmaf(xa.z, w, a[2]); a[3] = fmaf(xa.w, w, a[3]);
    a[4] = fmaf(xb.x, w, a[4]); a[5] = fmaf(xb.y, w, a[5]);
    a[6] = fmaf(xb.z, w, a[6]); a[7] = fmaf(xb.w, w, a[7]);
  }
  const float bb = b[o];
  const size_t base = (size_t)(r0 + half * 8) * ND + o;
#pragma unroll
  for (int j = 0; j < 8; ++j) y[base + (size_t)j * ND] = a[j] + bb;
}

// ---------------- CSR build ----------------
__global__ __launch_bounds__(256) void k_hist(const int* __restrict__ ei,
                                              int* __restrict__ hist) {
  int e = blockIdx.x * 256 + threadIdx.x;
  if (e < NE) atomicAdd(&hist[ei[e]], 1);
}

__global__ __launch_bounds__(256) void k_scan1(const int* __restrict__ hist,
                                               int* __restrict__ off,
                                               int* __restrict__ bsum) {
  __shared__ int sh[256];
  const int tid = threadIdx.x;
  const int idx = blockIdx.x * 256 + tid;
  int v = (idx < NN) ? hist[idx] : 0;
  sh[tid] = v;
  __syncthreads();
#pragma unroll
  for (int d = 1; d < 256; d <<= 1) {
    int t = (tid >= d) ? sh[tid - d] : 0;
    __syncthreads();
    sh[tid] += t;
    __syncthreads();
  }
  if (idx < NN) off[idx] = sh[tid] - v;
  if (tid == 255) bsum[blockIdx.x] = sh[255];
}

__global__ __launch_bounds__(256) void k_scan2(int* __restrict__ bsum) {
  __shared__ int sh[256];
  const int tid = threadIdx.x;
  int v = (tid < SCAN_NBLK) ? bsum[tid] : 0;
  sh[tid] = v;
  __syncthreads();
#pragma unroll
  for (int d = 1; d < 256; d <<= 1) {
    int t = (tid >= d) ? sh[tid - d] : 0;
    __syncthreads();
    sh[tid] += t;
    __syncthreads();
  }
  if (tid < SCAN_NBLK) bsum[tid] = sh[tid] - v;
}

__global__ __launch_bounds__(256) void k_scan3(int* __restrict__ off,
                                               const int* __restrict__ bsum,
                                               int* __restrict__ cursor) {
  const int idx = blockIdx.x * 256 + threadIdx.x;
  if (idx < NN) {
    int o = off[idx] + bsum[blockIdx.x];
    off[idx] = o;
    cursor[idx] = o;
  }
  if (blockIdx.x == 0 && threadIdx.x == 0) off[NN] = NE;
}

__global__ __launch_bounds__(256) void k_scatter(const int* __restrict__ ei,
                                                 int* __restrict__ cursor,
                                                 int2* __restrict__ pair) {
  int e = blockIdx.x * 256 + threadIdx.x;
  if (e >= NE) return;
  int row = ei[e];
  int col = ei[NE + e];
  int pos = atomicAdd(&cursor[row], 1);
  pair[pos] = make_int2(col, e);
}

// ---------------- fused gather: clamped-prefetch pipeline, single LDS buffer ----
// 32 lanes/node, lane l=(h<<2)|q. Chunk = 8 edges. All prefetch indices are
// clamped to the node's last edge (dup L1-hit reads, zero wasted fetch).
// Per iter t: issue K/V(t,4-7); [lgkmcnt] compute 0-3; compute 4-7;
//             ds_write ea(t+1); load ea(t+2)->regs; cols(t+1)+issue K/V(t+1,0-3).
// Same-buffer write-after-read is safe: per-wave LDS ops execute in order.
#define EA_ACC(sc, cidx) do { \
  const float4* _ep = (const float4*)(ldsb + (cidx) * ED + q * 16); \
  float4 _a; \
  _a = _ep[0]; sc = fmaf(_a.x, gg[0], sc);  sc = fmaf(_a.y, gg[1], sc);  sc = fmaf(_a.z, gg[2], sc);  sc = fmaf(_a.w, gg[3], sc); \
  _a = _ep[1]; sc = fmaf(_a.x, gg[4], sc);  sc = fmaf(_a.y, gg[5], sc);  sc = fmaf(_a.z, gg[6], sc);  sc = fmaf(_a.w, gg[7], sc); \
  _a = _ep[2]; sc = fmaf(_a.x, gg[8], sc);  sc = fmaf(_a.y, gg[9], sc);  sc = fmaf(_a.z, gg[10], sc); sc = fmaf(_a.w, gg[11], sc); \
  _a = _ep[3]; sc = fmaf(_a.x, gg[12], sc); sc = fmaf(_a.y, gg[13], sc); sc = fmaf(_a.z, gg[14], sc); sc = fmaf(_a.w, gg[15], sc); \
} while (0)

#define FINISH(sc, vv, validc) do { \
  sc += __shfl_xor(sc, 1); sc += __shfl_xor(sc, 2); \
  float _es = (validc) ? __expf(fmaf(sc, 0.25f, sb)) : 0.f; \
  den += _es; \
  acc.x = fmaf(_es, (vv).x, acc.x); acc.y = fmaf(_es, (vv).y, acc.y); \
  acc.z = fmaf(_es, (vv).z, acc.z); acc.w = fmaf(_es, (vv).w, acc.w); \
} while (0)

__global__ __launch_bounds__(256) void k_gather(const float* __restrict__ Q,
                                                const float* __restrict__ K,
                                                const float* __restrict__ V,
                                                const float* __restrict__ we,
                                                const float* __restrict__ be,
                                                const float* __restrict__ ea,
                                                const int* __restrict__ off,
                                                const int2* __restrict__ pair,
                                                float* __restrict__ msgn) {
  __shared__ float eas[8][8 * ED];   // single buffer: 16 KB/block
  const int g = threadIdx.x >> 5;
  const int n = blockIdx.x * 8 + g;
  const int l = threadIdx.x & 31;
  const int h = l >> 2;
  const int q = l & 3;
  const int me = l >> 2;   // staged edge (0..7)
  const int mp = l & 3;    // staged float4-part

  // ---- per-node setup: Q frag, sb, gg ----
  float qf[DK];
  {
    const float4* qp = (const float4*)(Q + (size_t)n * ND + h * DK);
#pragma unroll
    for (int i = 0; i < 4; ++i) {
      float4 v = qp[i];
      qf[4 * i + 0] = v.x; qf[4 * i + 1] = v.y;
      qf[4 * i + 2] = v.z; qf[4 * i + 3] = v.w;
    }
  }
  float sbase = 0.f;
  {
    const float4* bp = (const float4*)(be + h * DK);
#pragma unroll
    for (int i = 0; i < 4; ++i) {
      float4 b = bp[i];
      sbase = fmaf(qf[4 * i + 0], b.x, sbase);
      sbase = fmaf(qf[4 * i + 1], b.y, sbase);
      sbase = fmaf(qf[4 * i + 2], b.z, sbase);
      sbase = fmaf(qf[4 * i + 3], b.w, sbase);
    }
  }
  const float sb = sbase * 0.25f;

  float gg[16];
#pragma unroll
  for (int jj = 0; jj < 16; ++jj) {
    const float4* wp = (const float4*)(we + (size_t)(q * 16 + jj) * ND + h * DK);
    float s = 0.f;
#pragma unroll
    for (int i = 0; i < 4; ++i) {
      float4 w = wp[i];
      s = fmaf(qf[4 * i + 0], w.x, s);
      s = fmaf(qf[4 * i + 1], w.y, s);
      s = fmaf(qf[4 * i + 2], w.z, s);
      s = fmaf(qf[4 * i + 3], w.w, s);
    }
    gg[jj] = s;
  }

  float4 qv;
  qv.x = qf[q * 4 + 0]; qv.y = qf[q * 4 + 1];
  qv.z = qf[q * 4 + 2]; qv.w = qf[q * 4 + 3];

  const int j0 = off[n], j1 = off[n + 1];
  const int nch = (j1 - j0 + 7) >> 3;
  const int jlast = j1 - 1;
  const int hq = h * DK + q * 4;

  float4 acc = make_float4(0.f, 0.f, 0.f, 0.f);
  float den = 0.f;

  if (nch > 0) {
    // ---- prologue: ea(0) -> LDS, ea(1) -> regs, cols(0) + K/V(0, 0-3) ----
    {
      const int eid = pair[min(j0 + me, jlast)].y;
      const float4* s = (const float4*)(ea + (size_t)eid * ED) + mp;
      float4 a0 = s[0], a1 = s[4], a2 = s[8], a3 = s[12];
      float4* d = (float4*)&eas[g][me * ED] + mp;
      d[0] = a0; d[4] = a1; d[8] = a2; d[12] = a3;
    }
    float4 er0, er1, er2, er3;
    {
      const int eid = pair[min(j0 + 8 + me, jlast)].y;
      const float4* s = (const float4*)(ea + (size_t)eid * ED) + mp;
      er0 = s[0]; er1 = s[4]; er2 = s[8]; er3 = s[12];
    }
    int cc0 = pair[min(j0 + 0, jlast)].x, cc1 = pair[min(j0 + 1, jlast)].x;
    int cc2 = pair[min(j0 + 2, jlast)].x, cc3 = pair[min(j0 + 3, jlast)].x;
    int cc4 = pair[min(j0 + 4, jlast)].x, cc5 = pair[min(j0 + 5, jlast)].x;
    int cc6 = pair[min(j0 + 6, jlast)].x, cc7 = pair[min(j0 + 7, jlast)].x;
    float4 kA0 = *(const float4*)(K + (size_t)cc0 * ND + hq);
    float4 kA1 = *(const float4*)(K + (size_t)cc1 * ND + hq);
    float4 kA2 = *(const float4*)(K + (size_t)cc2 * ND + hq);
    float4 kA3 = *(const float4*)(K + (size_t)cc3 * ND + hq);
    float4 vA0 = *(const float4*)(V + (size_t)cc0 * ND + hq);
    float4 vA1 = *(const float4*)(V + (size_t)cc1 * ND + hq);
    float4 vA2 = *(const float4*)(V + (size_t)cc2 * ND + hq);
    float4 vA3 = *(const float4*)(V + (size_t)cc3 * ND + hq);

    const float* ldsb = &eas[g][0];
    for (int t = 0; t < nch; ++t) {
      const int jp = j0 + t * 8;

      // A: issue K/V for edges 4-7 of chunk t
      float4 kB0 = *(const float4*)(K + (size_t)cc4 * ND + hq);
      float4 kB1 = *(const float4*)(K + (size_t)cc5 * ND + hq);
      float4 kB2 = *(const float4*)(K + (size_t)cc6 * ND + hq);
      float4 kB3 = *(const float4*)(K + (size_t)cc7 * ND + hq);
      float4 vB0 = *(const float4*)(V + (size_t)cc4 * ND + hq);
      float4 vB1 = *(const float4*)(V + (size_t)cc5 * ND + hq);
      float4 vB2 = *(const float4*)(V + (size_t)cc6 * ND + hq);
      float4 vB3 = *(const float4*)(V + (size_t)cc7 * ND + hq);

      // B: pair line for ea(t+2), clamped
      const int eidN = pair[min(jp + 16 + me, jlast)].y;

      // C: wait for LDS (prev ds_write + staging), then compute edges 0-3
      asm volatile("s_waitcnt lgkmcnt(0)" ::: "memory");
      __builtin_amdgcn_sched_barrier(0);
      {
        float s0 = fmaf(qv.w, kA0.w, fmaf(qv.z, kA0.z, fmaf(qv.y, kA0.y, kA0.x * qv.x)));
        float s1 = fmaf(qv.w, kA1.w, fmaf(qv.z, kA1.z, fmaf(qv.y, kA1.y, kA1.x * qv.x)));
        float s2 = fmaf(qv.w, kA2.w, fmaf(qv.z, kA2.z, fmaf(qv.y, kA2.y, kA2.x * qv.x)));
        float s3 = fmaf(qv.w, kA3.w, fmaf(qv.z, kA3.z, fmaf(qv.y, kA3.y, kA3.x * qv.x)));
        EA_ACC(s0, 0); EA_ACC(s1, 1); EA_ACC(s2, 2); EA_ACC(s3, 3);
        FINISH(s0, vA0, jp + 0 < j1);
        FINISH(s1, vA1, jp + 1 < j1);
        FINISH(s2, vA2, jp + 2 < j1);
        FINISH(s3, vA3, jp + 3 < j1);
      }

      // D: compute edges 4-7
      {
        float s0 = fmaf(qv.w, kB0.w, fmaf(qv.z, kB0.z, fmaf(qv.y, kB0.y, kB0.x * qv.x)));
        float s1 = fmaf(qv.w, kB1.w, fmaf(qv.z, kB1.z, fmaf(qv.y, kB1.y, kB1.x * qv.x)));
        float s2 = fmaf(qv.w, kB2.w, fmaf(qv.z, kB2.z, fmaf(qv.y, kB2.y, kB2.x * qv.x)));
        float s3 = fmaf(qv.w, kB3.w, fmaf(qv.z, kB3.z, fmaf(qv.y, kB3.y, kB3.x * qv.x)));
        EA_ACC(s0, 4); EA_ACC(s1, 5); EA_ACC(s2, 6); EA_ACC(s3, 7);
        FINISH(s0, vB0, jp + 4 < j1);
        FINISH(s1, vB1, jp + 5 < j1);
        FINISH(s2, vB2, jp + 6 < j1);
        FINISH(s3, vB3, jp + 7 < j1);
      }

      // E: ds_write ea(t+1) into same buffer (wave LDS ops are in-order)
      {
        float4* d = (float4*)&eas[g][me * ED] + mp;
        d[0] = er0; d[4] = er1; d[8] = er2; d[12] = er3;
      }

      // F: load ea(t+2) -> regs
      {
        const float4* s = (const float4*)(ea + (size_t)eidN * ED) + mp;
        er0 = s[0]; er1 = s[4]; er2 = s[8]; er3 = s[12];
      }

      // G: cols(t+1) clamped + issue K/V(t+1, edges 0-3)
      cc0 = pair[min(jp + 8,  jlast)].x; cc1 = pair[min(jp + 9,  jlast)].x;
      cc2 = pair[min(jp + 10, jlast)].x; cc3 = pair[min(jp + 11, jlast)].x;
      cc4 = pair[min(jp + 12, jlast)].x; cc5 = pair[min(jp + 13, jlast)].x;
      cc6 = pair[min(jp + 14, jlast)].x; cc7 = pair[min(jp + 15, jlast)].x;
      kA0 = *(const float4*)(K + (size_t)cc0 * ND + hq);
      kA1 = *(const float4*)(K + (size_t)cc1 * ND + hq);
      kA2 = *(const float4*)(K + (size_t)cc2 * ND + hq);
      kA3 = *(const float4*)(K + (size_t)cc3 * ND + hq);
      vA0 = *(const float4*)(V + (size_t)cc0 * ND + hq);
      vA1 = *(const float4*)(V + (size_t)cc1 * ND + hq);
      vA2 = *(const float4*)(V + (size_t)cc2 * ND + hq);
      vA3 = *(const float4*)(V + (size_t)cc3 * ND + hq);
    }
  }

  const float inv = 1.f / (den + 1e-8f);
  float4 o;
  o.x = acc.x * inv; o.y = acc.y * inv; o.z = acc.z * inv; o.w = acc.w * inv;
  *(float4*)(msgn + (size_t)n * ND + h * DK + q * 4) = o;
}

extern "C" void kernel_launch(void* const* d_in, const int* in_sizes, int n_in,
                              void* d_out, int out_size, void* d_ws, size_t ws_size,
                              hipStream_t stream) {
  const float* nodes = (const float*)d_in[0];
  const int*   ei    = (const int*)d_in[1];
  const float* ea    = (const float*)d_in[2];
  const float* wq    = (const float*)d_in[3];
  const float* bq    = (const float*)d_in[4];
  const float* wk    = (const float*)d_in[5];
  const float* bk    = (const float*)d_in[6];
  const float* wv    = (const float*)d_in[7];
  const float* bv    = (const float*)d_in[8];
  const float* we    = (const float*)d_in[9];
  const float* be    = (const float*)d_in[10];
  const float* wo    = (const float*)d_in[11];
  const float* bo    = (const float*)d_in[12];
  float* out = (float*)d_out;

  float* ws = (float*)d_ws;
  const size_t NND = (size_t)NN * ND;
  float* Q    = ws;
  float* K    = Q + NND;
  float* V    = K + NND;
  float* msgn = V + NND;
  int* hist   = (int*)(msgn + NND);
  int* off    = hist + NN;            // NN+1 (padded to 40004)
  int* cursor = off + 40004;
  int* bsum   = cursor + NN;
  int2* pair  = (int2*)(bsum + 256);  // NE int2

  hipMemsetAsync(hist, 0, NN * sizeof(int), stream);

  dim3 blk(256);

  proj_qkv<<<dim3(NN / 16), blk, 0, stream>>>(nodes, wq, bq, wk, bk, wv, bv, Q, K, V);

  dim3 gE((NE + 255) / 256);
  k_hist<<<gE, blk, 0, stream>>>(ei, hist);
  k_scan1<<<dim3(SCAN_NBLK), blk, 0, stream>>>(hist, off, bsum);
  k_scan2<<<dim3(1), blk, 0, stream>>>(bsum);
  k_scan3<<<dim3(SCAN_NBLK), blk, 0, stream>>>(off, bsum, cursor);
  k_scatter<<<gE, blk, 0, stream>>>(ei, cursor, pair);

  k_gather<<<dim3(NN / 8), blk, 0, stream>>>(Q, K, V, we, be, ea, off, pair, msgn);

  proj128<<<dim3(NN / 16), blk, 0, stream>>>(msgn, wo, bo, out);
}